// Round 6
// baseline (140.173 us; speedup 1.0000x reference)
//
#include <hip/hip_runtime.h>
#include <hip/hip_bf16.h>
#include <math.h>

// Problem constants
#define BB 4
#define CC 64
#define HH 128
#define WW 128
#define HW 16384
#define CHW (CC*HW)

typedef __bf16 bf16;
typedef __attribute__((ext_vector_type(8))) __bf16 bf16x8;
typedef __attribute__((ext_vector_type(4))) __bf16 bf16x4;
typedef __attribute__((ext_vector_type(4))) float f32x4;
typedef __attribute__((ext_vector_type(4))) unsigned short u16x4;

#define MFMA(a, b, c) __builtin_amdgcn_mfma_f32_16x16x32_bf16((a), (b), (c), 0, 0, 0)

// ---- Pre-kernel: x NCHW -> NHWC bf16 (blocks 0..1023) + weight frags ----
__global__ __launch_bounds__(256) void k_pre(const float* __restrict__ x,
        bf16* __restrict__ xt,
        const float* __restrict__ dw, const float* __restrict__ ow,
        const float* __restrict__ mw,
        bf16* __restrict__ wfd_hi,
        bf16* __restrict__ wfo_hi, bf16* __restrict__ wfo_lo) {
    __shared__ float tile[64][65];
    if (blockIdx.x < 1024) {
        int b  = blockIdx.x >> 8;
        int s0 = (blockIdx.x & 255) * 64;
        int t  = threadIdx.x;
        const float* xb = x + (size_t)b * CHW;
        // load 64ch x 64sp tile, float4 per thread
        int sl = (t & 15) * 4;
        int c0 = t >> 4;                            // 0..15
        #pragma unroll
        for (int r = 0; r < 4; ++r) {
            int c = c0 + r * 16;
            float4 v = *(const float4*)&xb[(size_t)c * HW + s0 + sl];
            tile[c][sl]     = v.x;
            tile[c][sl + 1] = v.y;
            tile[c][sl + 2] = v.z;
            tile[c][sl + 3] = v.w;
        }
        __syncthreads();
        // write: lane l of wave w: si = w*16 + (l>>2), ch-group = (l&3)*16
        int lane = t & 63, w = t >> 6;
        int si = w * 16 + (lane >> 2);
        int cg = (lane & 3) * 16;
        bf16x8 h0, h1;
        #pragma unroll
        for (int j = 0; j < 8; ++j) {
            h0[j] = (bf16)tile[cg + j][si];
            h1[j] = (bf16)tile[cg + 8 + j][si];
        }
        bf16* dst = xt + (size_t)b * CHW + (size_t)(s0 + si) * 64 + cg;
        *(bf16x8*)dst       = h0;
        *(bf16x8*)(dst + 8) = h1;
    } else {
        int idx = (blockIdx.x - 1024) * 256 + threadIdx.x;
        if (idx < 36864) {                          // deform frags (hi only): 4 nt * 18 ks * 64 * 8
            int j    = idx & 7;
            int lane = (idx >> 3) & 63;
            int ks   = (idx >> 9) % 18;
            int nt   = idx / (512 * 18);
            int n    = nt * 16 + (lane & 15);
            int kglob = ks * 32 + (lane >> 4) * 8 + j;
            int kk = kglob >> 6, c = kglob & 63;    // K-order: k = kk*64 + c
            wfd_hi[idx] = (bf16)dw[(n * 64 + c) * 9 + kk];
        } else {
            int idx2 = idx - 36864;                 // offmask frags: 2 nt
            int j    = idx2 & 7;
            int lane = (idx2 >> 3) & 63;
            int ks   = (idx2 >> 9) % 18;
            int nt   = idx2 / (512 * 18);
            int ch   = nt * 16 + (lane & 15);
            int kglob = ks * 32 + (lane >> 4) * 8 + j;
            int kk = kglob >> 6, c = kglob & 63;
            float w = 0.0f;
            if (ch < 18)      w = ow[(ch * 64 + c) * 9 + kk];
            else if (ch < 27) w = mw[((ch - 18) * 64 + c) * 9 + kk];
            bf16 h = (bf16)w;
            wfo_hi[idx2] = h;
            wfo_lo[idx2] = (bf16)(w - (float)h);
        }
    }
}

// ---- Fused offmask-conv + deformable conv, 64 positions / block ----
// B : offset/mask GEMM, wave = st (16 pos), A direct from global -> om_s
// C1: 576 tasks: bilinear scalars -> sampw (bf16x4), sampo (u16x4)
// D : wave = st; lane (m,g) gathers ITS OWN A-fragments (8 ch slices) in
//     registers and runs 8 MFMA per kk across all 4 o-tiles. No LDS, no syncs.
__global__ __launch_bounds__(256, 4) void k_fused(const bf16* __restrict__ xt,
        const bf16* __restrict__ wfo_hi, const bf16* __restrict__ wfo_lo,
        const bf16* __restrict__ wfd_hi,
        const float* __restrict__ ob, const float* __restrict__ mb,
        const float* __restrict__ db, float* __restrict__ out) {
    __shared__ float om_s[27 * 64];                     // 6912 B
    __shared__ __align__(8) bf16 sampw[576 * 4];        // 4608 B
    __shared__ __align__(8) unsigned short sampo[576 * 4]; // 4608 B

    int pos0 = blockIdx.x * 64;
    int wo0 = pos0 & 127;
    int ho  = (pos0 >> 7) & 127;
    int b   = pos0 >> 14;
    int t = threadIdx.x, wave = t >> 6, lane = t & 63;
    int m = lane & 15, g = lane >> 4;
    const bf16* xtb = xt + (size_t)b * CHW;

    // ---- Phase B: offset/mask GEMM, wave = st ----
    {
        int st = wave;
        f32x4 acc0 = {0.f, 0.f, 0.f, 0.f};
        f32x4 acc1 = {0.f, 0.f, 0.f, 0.f};
        const bf16x8* bh0 = (const bf16x8*)wfo_hi + lane;
        const bf16x8* bl0 = (const bf16x8*)wfo_lo + lane;
        const bf16x8* bh1 = (const bf16x8*)wfo_hi + 18 * 64 + lane;
        const bf16x8* bl1 = (const bf16x8*)wfo_lo + 18 * 64 + lane;
        #pragma unroll
        for (int kk = 0; kk < 9; ++kk) {
            int y  = ho + kk / 3 - 1;
            int xx = wo0 + st * 16 + m + (kk % 3) - 1;
            bf16x8 ae = {};
            bf16x8 ao = {};
            if ((unsigned)y < 128u && (unsigned)xx < 128u) {
                const bf16* bp = xtb + ((size_t)(y * 128 + xx) << 6);
                ae = *(const bf16x8*)(bp + g * 8);
                ao = *(const bf16x8*)(bp + 32 + g * 8);
            }
            int ks0 = 2 * kk, ks1 = 2 * kk + 1;
            acc0 = MFMA(ae, bh0[ks0 * 64], acc0);
            acc0 = MFMA(ae, bl0[ks0 * 64], acc0);
            acc0 = MFMA(ao, bh0[ks1 * 64], acc0);
            acc0 = MFMA(ao, bl0[ks1 * 64], acc0);
            acc1 = MFMA(ae, bh1[ks0 * 64], acc1);
            acc1 = MFMA(ae, bl1[ks0 * 64], acc1);
            acc1 = MFMA(ao, bh1[ks1 * 64], acc1);
            acc1 = MFMA(ao, bl1[ks1 * 64], acc1);
        }
        int p64 = st * 16 + g * 4;
        float bias0 = ob[m];                        // ch = m < 16, offset rows
        #pragma unroll
        for (int r = 0; r < 4; ++r)
            om_s[m * 64 + p64 + r] = acc0[r] + bias0;
        int ch1 = 16 + m;
        if (ch1 < 27) {
            float bias1 = (ch1 < 18) ? ob[ch1] : mb[ch1 - 18];
            #pragma unroll
            for (int r = 0; r < 4; ++r) {
                float v = acc1[r] + bias1;
                if (ch1 >= 18) v = 1.0f / (1.0f + __expf(-v));
                om_s[ch1 * 64 + p64 + r] = v;
            }
        }
    }
    __syncthreads();

    // ---- Phase C1: bilinear scalar precompute (576 tasks) ----
    for (int task = t; task < 576; task += 256) {
        int p64 = task / 9, k = task - p64 * 9;
        float dy = om_s[(2 * k) * 64 + p64];
        float dx = om_s[(2 * k + 1) * 64 + p64];
        float mk = om_s[(18 + k) * 64 + p64];
        float py = (float)(ho - 1 + k / 3) + dy;
        float px = (float)(wo0 + p64 - 1 + (k % 3)) + dx;
        float y0f = floorf(py), x0f = floorf(px);
        float fy = py - y0f, fx = px - x0f;
        int y0 = (int)y0f, x0 = (int)x0f;
        int y1 = y0 + 1,  x1 = x0 + 1;
        bool vy0 = (unsigned)y0 < 128u, vy1 = (unsigned)y1 < 128u;
        bool vx0 = (unsigned)x0 < 128u, vx1 = (unsigned)x1 < 128u;
        int y0c = min(max(y0, 0), 127), y1c = min(max(y1, 0), 127);
        int x0c = min(max(x0, 0), 127), x1c = min(max(x1, 0), 127);
        bf16x4 wv;
        wv.x = (bf16)((vy0 && vx0) ? mk * (1.f - fy) * (1.f - fx) : 0.f);
        wv.y = (bf16)((vy0 && vx1) ? mk * (1.f - fy) * fx         : 0.f);
        wv.z = (bf16)((vy1 && vx0) ? mk * fy * (1.f - fx)         : 0.f);
        wv.w = (bf16)((vy1 && vx1) ? mk * fy * fx                 : 0.f);
        u16x4 ov;
        ov.x = (unsigned short)(y0c * 128 + x0c);
        ov.y = (unsigned short)(y0c * 128 + x1c);
        ov.z = (unsigned short)(y1c * 128 + x0c);
        ov.w = (unsigned short)(y1c * 128 + x1c);
        *(bf16x4*)&sampw[task * 4] = wv;
        *(u16x4*)&sampo[task * 4] = ov;
    }
    __syncthreads();

    // ---- Phase D: register-resident gather + MFMA, wave = st ----
    {
        int st = wave;
        f32x4 acc[4];
        #pragma unroll
        for (int nt = 0; nt < 4; ++nt) acc[nt] = (f32x4){0.f, 0.f, 0.f, 0.f};
        const bf16x8* bhd = (const bf16x8*)wfd_hi + lane;
        int taskbase = (st * 16 + m) * 9;
        int cb0 = g * 8;                            // par=0 channel slice
        int cb1 = 32 + g * 8;                       // par=1 channel slice
        #pragma unroll
        for (int kk = 0; kk < 9; ++kk) {
            int task = taskbase + kk;
            bf16x4 wb = *(const bf16x4*)&sampw[task * 4];
            u16x4  o4 = *(const u16x4*)&sampo[task * 4];
            float w00 = (float)wb.x, w01 = (float)wb.y;
            float w10 = (float)wb.z, w11 = (float)wb.w;
            const bf16* p00 = xtb + ((int)o4.x << 6);
            const bf16* p01 = xtb + ((int)o4.y << 6);
            const bf16* p10 = xtb + ((int)o4.z << 6);
            const bf16* p11 = xtb + ((int)o4.w << 6);
            bf16x8 e00 = *(const bf16x8*)(p00 + cb0);
            bf16x8 e01 = *(const bf16x8*)(p01 + cb0);
            bf16x8 e10 = *(const bf16x8*)(p10 + cb0);
            bf16x8 e11 = *(const bf16x8*)(p11 + cb0);
            bf16x8 d00 = *(const bf16x8*)(p00 + cb1);
            bf16x8 d01 = *(const bf16x8*)(p01 + cb1);
            bf16x8 d10 = *(const bf16x8*)(p10 + cb1);
            bf16x8 d11 = *(const bf16x8*)(p11 + cb1);
            bf16x8 a0, a1;
            #pragma unroll
            for (int j = 0; j < 8; ++j) {
                float r0 = w00 * (float)e00[j] + w01 * (float)e01[j]
                         + w10 * (float)e10[j] + w11 * (float)e11[j];
                float r1 = w00 * (float)d00[j] + w01 * (float)d01[j]
                         + w10 * (float)d10[j] + w11 * (float)d11[j];
                a0[j] = (bf16)r0;
                a1[j] = (bf16)r1;
            }
            int ks0 = 2 * kk, ks1 = 2 * kk + 1;
            #pragma unroll
            for (int nt = 0; nt < 4; ++nt) {
                acc[nt] = MFMA(a0, bhd[(nt * 18 + ks0) * 64], acc[nt]);
                acc[nt] = MFMA(a1, bhd[(nt * 18 + ks1) * 64], acc[nt]);
            }
        }
        #pragma unroll
        for (int nt = 0; nt < 4; ++nt) {
            int o = nt * 16 + m;
            float bias = db[o];
            float4 vv = {acc[nt][0] + bias, acc[nt][1] + bias,
                         acc[nt][2] + bias, acc[nt][3] + bias};
            *(float4*)&out[((size_t)(b * 64 + o)) * HW + ho * 128 + wo0 + st * 16 + g * 4] = vv;
        }
    }
}

extern "C" void kernel_launch(void* const* d_in, const int* in_sizes, int n_in,
                              void* d_out, int out_size, void* d_ws, size_t ws_size,
                              hipStream_t stream) {
    const float* x   = (const float*)d_in[0];
    const float* ow  = (const float*)d_in[1];
    const float* ob  = (const float*)d_in[2];
    const float* mw  = (const float*)d_in[3];
    const float* mb  = (const float*)d_in[4];
    const float* dw  = (const float*)d_in[5];
    const float* db  = (const float*)d_in[6];
    float* out = (float*)d_out;

    bf16* xt = (bf16*)d_ws;                         // 4,194,304 bf16 = 8 MB
    bf16* wfd_hi = xt + (size_t)BB * HW * CC;       // 36864
    bf16* wfo_hi = wfd_hi + 36864;                  // 18432
    bf16* wfo_lo = wfo_hi + 18432;                  // 18432

    k_pre<<<1024 + 216, 256, 0, stream>>>(x, xt, dw, ow, mw, wfd_hi, wfo_hi, wfo_lo);
    k_fused<<<(BB * HW) / 64, 256, 0, stream>>>(xt, wfo_hi, wfo_lo, wfd_hi, ob, mb, db, out);
}